// Round 6
// baseline (631.915 us; speedup 1.0000x reference)
//
#include <hip/hip_runtime.h>
#include <hip/hip_bf16.h>

// MetaNetImageEncoder on MI355X — round 6.
// Post-mortem r5: ntile-XCD pinning + grid 512 regressed (123us; occ 22%,
// FETCH 91MB — A panels pulled by 8 XCDs). Root cause of the stable ~88us
// floor (r1=r4): bulk-synchronous k-loop — __syncthreads drains vmcnt(0)
// every iter, so the full memory round trip is on the critical path
// (MfmaUtil 8.5%, everything idle). Fix = AITER-style pipeline:
//  * double-buffered LDS; stage tile k+1 BEFORE waiting; manual
//    `s_waitcnt vmcnt(5)` (tile-k+1 stays in flight) + raw s_barrier
//    (no full drain). Manual counts are conservative-safe vs extra vmem.
//  * G=2 samples/block: B mixed once for 2 samples -> phase-B weight
//    traffic halved to 664MB (L2-resident strips via ntile->XCD pinning,
//    grid dim3(12,2,32): bid%8 spreads nt, strips ~2MB/XCD).
//  * 768 blocks, 3/CU, 12 waves/CU. BM=128(G=2), BN=64, BK=32.
//
// MFMA 16x16x32 bf16 layouts (learn_hip m89):
//   A-frag: A[m=lane&15][k=(lane>>4)*8+j], B-frag: B[k=(lane>>4)*8+j][n=lane&15]
//   C/D:    col=lane&15, row=(lane>>4)*4+reg

typedef __bf16 bf16x8 __attribute__((ext_vector_type(8)));
typedef float f32x4 __attribute__((ext_vector_type(4)));
typedef __hip_bfloat16 bf16;

struct alignas(16) BF8 { bf16 h[8]; };

constexpr int BATCH = 64;
constexpr int NP    = 196;
constexpr int NPAD  = 256;
constexpr int DIM   = 768;
constexpr int NT    = 8;
constexpr size_t MSZ = (size_t)DIM * DIM;
constexpr int KT    = 24;    // K tiles of 32

__device__ __forceinline__ void async_cp16(const void* g, void* l) {
  __builtin_amdgcn_global_load_lds(
      (const __attribute__((address_space(1))) uint32_t*)g,
      (__attribute__((address_space(3))) uint32_t*)l, 16, 0, 0);
}

// ---------------- K1: patchify + cast to bf16, pad rows to 256 ----------------
__global__ void k_patchify(const float* __restrict__ x, bf16* __restrict__ A) {
  int idx  = blockIdx.x * blockDim.x + threadIdx.x;
  int col4 = idx % (DIM / 4);
  int row  = idx / (DIM / 4);
  int d = col4 * 4;
  int b = row >> 8;
  int n = row & 255;
  bf16 tmp[4];
  if (n < NP) {
    int hp = n / 14, wp = n % 14;
    int c  = d >> 8;
    int rr = d & 255;
    int i = rr >> 4, j = rr & 15;
    const float* src = x + ((((size_t)b * 3 + c) * 224 + hp * 16 + i) * 224 + wp * 16 + j);
    float4 f = *(const float4*)src;
    tmp[0] = __float2bfloat16(f.x);
    tmp[1] = __float2bfloat16(f.y);
    tmp[2] = __float2bfloat16(f.z);
    tmp[3] = __float2bfloat16(f.w);
  } else {
    tmp[0] = tmp[1] = tmp[2] = tmp[3] = __float2bfloat16(0.0f);
  }
  *(ushort4*)(A + (size_t)row * DIM + d) = *(ushort4*)tmp;
}

// ---------------- K2: transpose + cast weights: WT[mat][n][k] = W[mat][k][n] ----------------
__global__ void k_transpose_cast(const float* __restrict__ W1, const float* __restrict__ dW1,
                                 const float* __restrict__ W2, const float* __restrict__ dW2,
                                 bf16* __restrict__ WT) {
  __shared__ float tile[32][33];
  int mat = blockIdx.z;
  const float* src;
  if      (mat == 0) src = W1;
  else if (mat <= 8) src = dW1 + (size_t)(mat - 1) * MSZ;
  else if (mat == 9) src = W2;
  else               src = dW2 + (size_t)(mat - 10) * MSZ;
  int n0 = blockIdx.x * 32;
  int k0 = blockIdx.y * 32;
  int tx = threadIdx.x & 31, ty = threadIdx.x >> 5;
#pragma unroll
  for (int r = ty; r < 32; r += 8)
    tile[r][tx] = src[(size_t)(k0 + r) * DIM + n0 + tx];
  __syncthreads();
  bf16* dst = WT + (size_t)mat * MSZ;
#pragma unroll
  for (int r = ty; r < 32; r += 8)
    dst[(size_t)(n0 + r) * DIM + k0 + tx] = __float2bfloat16(tile[tx][r]);
}

// ---------------- K3: pipelined per-sample-pair GEMM (+inline mix) + relu + pool -------------
// grid dim3(12 ntiles, 2 rowblocks, 32 sample-pairs) = 768 blocks.
// Block: 2 samples x 128 rows x 64 cols. 4 waves: wave w -> sample w&1, rowhalf w>>1,
// 64x64 -> acc 4x4, 16 MFMA/iter (BK=32, 24 iters).
// LDS XOR-swizzled granules (16B): A slot = s*512 + r*4 + ((c)^(r&3)); B similarly /64 rows.

template<int MIX>
__device__ __forceinline__ void stage_tile(const bf16* __restrict__ A, const bf16* __restrict__ WT,
                                           int b0, int rowbase, int n0, int kk, int tid,
                                           uint4* __restrict__ Ab, uint4* __restrict__ Bb,
                                           const float* __restrict__ c0,
                                           const float* __restrict__ c1) {
  if (MIX) {
    // 1. weight-granule loads (tile k): one (r,c) granule serves both samples
    int r = tid >> 2, cp = tid & 3, c = cp ^ (r & 3);
    const bf16* p0 = WT + (size_t)(n0 + r) * DIM + kk + c * 8;
    BF8 w = *(const BF8*)p0;
    BF8 dv[8];
#pragma unroll
    for (int t = 0; t < NT; t++) dv[t] = *(const BF8*)(p0 + (size_t)(1 + t) * MSZ);
    // 2. fence: keep mix loads ABOVE the async issues (so compiler's wait for
    //    the mix data leaves the tile-k+1 asyncs in flight)
    asm volatile("" ::: "memory");
    // 3. async A for this tile
#pragma unroll
    for (int i = 0; i < 4; i++) {
      int p = i * 256 + tid;
      int s = p >> 9, rr = (p >> 2) & 127, cc = (p & 3) ^ (rr & 3);
      async_cp16(A + ((size_t)(b0 + s) * NPAD + rowbase + rr) * DIM + kk + cc * 8,
                 (void*)(Ab + p));
    }
    // 4. mix + pack + ds_write (compiler emits vmcnt wait here that also
    //    retires the OLDER tile-k asyncs -> pipeline-correct)
    float m0[8], m1[8];
#pragma unroll
    for (int j = 0; j < 8; j++) { float wv = __bfloat162float(w.h[j]); m0[j] = wv; m1[j] = wv; }
#pragma unroll
    for (int t = 0; t < NT; t++) {
#pragma unroll
      for (int j = 0; j < 8; j++) {
        float d = __bfloat162float(dv[t].h[j]);
        m0[j] += c0[t] * d;
        m1[j] += c1[t] * d;
      }
    }
    BF8 o0, o1;
#pragma unroll
    for (int j = 0; j < 8; j++) { o0.h[j] = __float2bfloat16(m0[j]); o1.h[j] = __float2bfloat16(m1[j]); }
    Bb[tid]       = *(uint4*)&o0;
    Bb[256 + tid] = *(uint4*)&o1;
    asm volatile("s_waitcnt lgkmcnt(0)" ::: "memory");
  } else {
    // async A (4) + async B (1) = 5 loads
#pragma unroll
    for (int i = 0; i < 4; i++) {
      int p = i * 256 + tid;
      int s = p >> 9, rr = (p >> 2) & 127, cc = (p & 3) ^ (rr & 3);
      async_cp16(A + ((size_t)(b0 + s) * NPAD + rowbase + rr) * DIM + kk + cc * 8,
                 (void*)(Ab + p));
    }
    int r = tid >> 2, c = (tid & 3) ^ (r & 3);
    async_cp16(WT + (size_t)(n0 + r) * DIM + kk + c * 8, (void*)(Bb + tid));
  }
}

template<int MIX>
__global__ __launch_bounds__(256, 3)
void k_gemm_pool(const bf16* __restrict__ A,    // [64*256, 768]
                 const bf16* __restrict__ WT,   // mats 0..8 = W1T, dW1T[8]
                 const float* __restrict__ b1,
                 const float* __restrict__ db1,
                 const float* __restrict__ coefs,  // [64][8] (MIX only)
                 float* __restrict__ pooled) {     // f32 [64][768], pre-zeroed, atomicAdd
  __shared__ uint4 AslU[2][1024];   // [buf][s*512 + r*4 + swz(c)]   32KB
  __shared__ uint4 BslU[2][512];    // [buf][s*256 + r*4 + swz(c)]   16KB
  __shared__ float biasl[2][64];
  __shared__ float clS[2][NT];
  __shared__ float red[4][64];

  int nt = blockIdx.x, rb = blockIdx.y, sg = blockIdx.z;
  int n0 = nt * 64, rowbase = rb * 128, b0 = sg * 2;
  int tid = threadIdx.x;

  float c0[NT], c1[NT];
  if (MIX) {
    if (tid < 16) clS[tid >> 3][tid & 7] = coefs[(b0 + (tid >> 3)) * NT + (tid & 7)];
    __syncthreads();
#pragma unroll
    for (int t = 0; t < NT; t++) { c0[t] = clS[0][t]; c1[t] = clS[1][t]; }
  }
  if (tid < 128) {
    int s = tid >> 6, col = tid & 63;
    float bias = b1[n0 + col];
    if (MIX) {
#pragma unroll
      for (int t = 0; t < NT; t++) bias += clS[s][t] * db1[t * DIM + n0 + col];
    }
    biasl[s][col] = bias;
  }

  int wave = tid >> 6, lane = tid & 63;
  int quad = lane >> 4, l16 = lane & 15;
  int s = wave & 1, half = wave >> 1;
  f32x4 acc[4][4] = {};

  // prologue: stage tile 0 into buf 0
  stage_tile<MIX>(A, WT, b0, rowbase, n0, 0, tid, AslU[0], BslU[0], c0, c1);

  int buf = 0;
  for (int kt = 0; kt < KT; kt++) {
    if (kt + 1 < KT) {
      stage_tile<MIX>(A, WT, b0, rowbase, n0, (kt + 1) * 32, tid,
                      AslU[buf ^ 1], BslU[buf ^ 1], c0, c1);
      if (!MIX) asm volatile("s_waitcnt vmcnt(5)" ::: "memory");
    } else {
      asm volatile("s_waitcnt vmcnt(0)" ::: "memory");
    }
    __builtin_amdgcn_s_barrier();
    // MFMA on buf: 4 mf x 4 nf
    const uint4* Ab = AslU[buf];
    const uint4* Bb = BslU[buf];
    bf16x8 bfr[4];
#pragma unroll
    for (int nf = 0; nf < 4; nf++) {
      int brow = nf * 16 + l16;
      bfr[nf] = *(const bf16x8*)(Bb + (MIX ? s : 0) * 256 + brow * 4 + (quad ^ (brow & 3)));
    }
#pragma unroll
    for (int mf = 0; mf < 4; mf++) {
      int arow = half * 64 + mf * 16 + l16;
      bf16x8 af = *(const bf16x8*)(Ab + s * 512 + arow * 4 + (quad ^ (arow & 3)));
#pragma unroll
      for (int nf = 0; nf < 4; nf++)
        acc[mf][nf] = __builtin_amdgcn_mfma_f32_16x16x32_bf16(af, bfr[nf], acc[mf][nf], 0, 0, 0);
    }
    __builtin_amdgcn_s_barrier();
    buf ^= 1;
  }

  // epilogue: relu(acc + bias), mask pad rows, column sums
  float colsum[4];
#pragma unroll
  for (int nf = 0; nf < 4; nf++) {
    float bias = biasl[MIX ? s : s][nf * 16 + l16];   // per-sample bias
    float sum = 0.0f;
#pragma unroll
    for (int mf = 0; mf < 4; mf++) {
      int rbase = rowbase + half * 64 + mf * 16 + quad * 4;
#pragma unroll
      for (int r = 0; r < 4; r++) {
        if (rbase + r < NP) sum += fmaxf(acc[mf][nf][r] + bias, 0.0f);
      }
    }
    sum += __shfl_xor(sum, 16, 64);
    sum += __shfl_xor(sum, 32, 64);
    colsum[nf] = sum;
  }
  if (lane < 16) {
#pragma unroll
    for (int nf = 0; nf < 4; nf++) red[wave][nf * 16 + lane] = colsum[nf];
  }
  __syncthreads();
  if (tid < 128) {
    int ss = tid >> 6, col = tid & 63;
    float v = red[ss][col] + red[ss + 2][col];   // halves of sample ss
    atomicAdd(pooled + (size_t)(b0 + ss) * DIM + n0 + col, v * (1.0f / 196.0f));
  }
}

// ---------------- K5: small GEMM, M=64: Y[mat] = Af(f32->bf16) @ WT[matbase+mat] ------------
__global__ __launch_bounds__(256, 2)
void k_gemm2(const float* __restrict__ Af,    // [64][768] f32
             const bf16* __restrict__ WT,
             int matbase,
             const float* __restrict__ bias,  // [768] or null
             float* __restrict__ Y) {         // [nmat][64][768]
  __shared__ uint4 AslU[64 * 8];
  __shared__ uint4 BslU[64 * 8];
  int n0  = blockIdx.x * 64;
  int mat = blockIdx.y;
  int tid = threadIdx.x, wave = tid >> 6, lane = tid & 63;
  int quad = lane >> 4, l16 = lane & 15;
  f32x4 acc[4] = {};
  const bf16* Wm = WT + (size_t)(matbase + mat) * MSZ;
  for (int k0 = 0; k0 < DIM; k0 += 64) {
#pragma unroll
    for (int i = 0; i < 2; i++) {
      int g = tid + i * 256;
      int r = g >> 3, c = g & 7;
      const float* src = Af + (size_t)r * DIM + k0 + c * 8;
      float4 xa = ((const float4*)src)[0];
      float4 xb = ((const float4*)src)[1];
      BF8 o;
      o.h[0] = __float2bfloat16(xa.x); o.h[1] = __float2bfloat16(xa.y);
      o.h[2] = __float2bfloat16(xa.z); o.h[3] = __float2bfloat16(xa.w);
      o.h[4] = __float2bfloat16(xb.x); o.h[5] = __float2bfloat16(xb.y);
      o.h[6] = __float2bfloat16(xb.z); o.h[7] = __float2bfloat16(xb.w);
      AslU[r * 8 + (c ^ (r & 7))] = *(uint4*)&o;
      BslU[r * 8 + (c ^ (r & 7))] = *(const uint4*)(Wm + (size_t)(n0 + r) * DIM + k0 + c * 8);
    }
    __syncthreads();
    const bf16* As = (const bf16*)AslU;
    const bf16* Bs = (const bf16*)BslU;
#pragma unroll
    for (int ks = 0; ks < 2; ks++) {
      int brow = wave * 16 + l16;
      bf16x8 bfr = *(const bf16x8*)(Bs + (size_t)(brow * 8 + ((ks * 4 + quad) ^ (brow & 7))) * 8);
#pragma unroll
      for (int mf = 0; mf < 4; mf++) {
        int arow = mf * 16 + l16;
        bf16x8 af = *(const bf16x8*)(As + (size_t)(arow * 8 + ((ks * 4 + quad) ^ (arow & 7))) * 8);
        acc[mf] = __builtin_amdgcn_mfma_f32_16x16x32_bf16(af, bfr, acc[mf], 0, 0, 0);
      }
    }
    __syncthreads();
  }
#pragma unroll
  for (int mf = 0; mf < 4; mf++) {
#pragma unroll
    for (int r = 0; r < 4; r++) {
      int row = mf * 16 + quad * 4 + r;
      int col = n0 + wave * 16 + l16;
      float v = acc[mf][r];
      if (bias) v += bias[col];
      Y[((size_t)mat * 64 + row) * DIM + col] = v;
    }
  }
}

// ---------------- K6: MetaNet ----------------
__global__ void k_metanet(const float* __restrict__ base,
                          const float* __restrict__ mw1, const float* __restrict__ mb1,
                          const float* __restrict__ mw2, const float* __restrict__ mb2,
                          float* __restrict__ coefs) {
  __shared__ float bl[DIM];
  __shared__ float hl[192];
  int b = blockIdx.x, tid = threadIdx.x;   // 192 threads
  for (int i = tid; i < DIM; i += 192) bl[i] = base[(size_t)b * DIM + i];
  __syncthreads();
  float s = mb1[tid];
  for (int k = 0; k < DIM; k++) s += bl[k] * mw1[(size_t)k * 192 + tid];
  hl[tid] = fmaxf(s, 0.0f);
  __syncthreads();
  if (tid < NT) {
    float c = mb2[tid];
    for (int j = 0; j < 192; j++) c += hl[j] * mw2[(size_t)j * NT + tid];
    coefs[b * NT + tid] = c;
  }
}

// ---------------- K7: combine ----------------
__global__ void k_combine(const float* __restrict__ Y,
                          const float* __restrict__ coefs,
                          const float* __restrict__ b2,
                          const float* __restrict__ db2,
                          float* __restrict__ out) {
  int idx = blockIdx.x * 256 + threadIdx.x;
  int b = idx / DIM, e = idx % DIM;
  float v = Y[(size_t)b * DIM + e] + b2[e];
#pragma unroll
  for (int t = 0; t < NT; t++) {
    float c = coefs[b * NT + t];
    v += c * (Y[((size_t)(1 + t) * 64 + b) * DIM + e] + db2[(size_t)t * DIM + e]);
  }
  out[idx] = v;
}

extern "C" void kernel_launch(void* const* d_in, const int* in_sizes, int n_in,
                              void* d_out, int out_size, void* d_ws, size_t ws_size,
                              hipStream_t stream) {
  const float* x   = (const float*)d_in[0];
  const float* W1  = (const float*)d_in[1];
  const float* b1  = (const float*)d_in[2];
  const float* W2  = (const float*)d_in[3];
  const float* b2  = (const float*)d_in[4];
  const float* dW1 = (const float*)d_in[5];
  const float* db1 = (const float*)d_in[6];
  const float* dW2 = (const float*)d_in[7];
  const float* db2 = (const float*)d_in[8];
  const float* mw1 = (const float*)d_in[9];
  const float* mb1 = (const float*)d_in[10];
  const float* mw2 = (const float*)d_in[11];
  const float* mb2 = (const float*)d_in[12];
  float* out = (float*)d_out;
  (void)in_sizes; (void)n_in; (void)out_size; (void)ws_size;

  // workspace layout (bytes) — total ~48.8 MB
  char* ws = (char*)d_ws;
  bf16*  A_bf    = (bf16*) (ws);                 // 25,165,824
  bf16*  WT      = (bf16*) (ws + 25165824);      // 21,233,664 -> 46,399,488
  float* pooledA = (float*)(ws + 46399488);      //    196,608 -> 46,596,096
  float* pooledB = (float*)(ws + 46596096);      //    196,608 -> 46,792,704
  float* coefs   = (float*)(ws + 46792704);      //      2,048 -> 46,794,752
  float* base    = (float*)(ws + 46794752);      //    196,608 -> 46,991,360
  float* Y       = (float*)(ws + 46991360);      //  1,769,472 -> 48,760,832

  // zero pooled accumulators (pooledA+pooledB contiguous)
  hipMemsetAsync(pooledA, 0, 2 * 196608, stream);

  k_patchify<<<dim3((BATCH * NPAD * (DIM / 4)) / 256), 256, 0, stream>>>(x, A_bf);
  k_transpose_cast<<<dim3(24, 24, 18), 256, 0, stream>>>(W1, dW1, W2, dW2, WT);
  // phase A
  k_gemm_pool<0><<<dim3(12, 2, 32), 256, 0, stream>>>(A_bf, WT, b1, db1, nullptr, pooledA);
  k_gemm2<<<dim3(DIM / 64, 1), 256, 0, stream>>>(pooledA, WT, 9, b2, base);
  k_metanet<<<dim3(BATCH), 192, 0, stream>>>(base, mw1, mb1, mw2, mb2, coefs);
  // phase B (pipelined inline mix, G=2 samples/block)
  k_gemm_pool<1><<<dim3(12, 2, 32), 256, 0, stream>>>(A_bf, WT, b1, db1, coefs, pooledB);
  k_gemm2<<<dim3(DIM / 64, 9), 256, 0, stream>>>(pooledB, WT, 9, nullptr, Y);
  k_combine<<<dim3((BATCH * DIM) / 256), 256, 0, stream>>>(Y, coefs, b2, db2, out);
}

// Round 7
// 536.710 us; speedup vs baseline: 1.1774x; 1.1774x over previous
//
#include <hip/hip_runtime.h>
#include <hip/hip_bf16.h>

// MetaNetImageEncoder on MI355X — round 7.
// Post-mortem r6: per-lane-varying LDS destination passed to global_load_lds
// (must be WAVE-UNIFORM; HW adds lane*16 itself) -> compiler emitted a
// per-lane/scratch lowering: FETCH 1.07GB, WRITE 632MB (scratch), 402us.
// r7 = r6's double-buffered vmcnt-pipelined k-loop with the staging fixed to
// the proven r4 form: LDS dst = base + wave*K + i*64 (uniform), global src
// enumerates slot p = wave*K + i*64 + lane with the XOR swizzle folded in.
//
// MFMA 16x16x32 bf16 layouts (learn_hip m89):
//   A-frag: A[m=lane&15][k=(lane>>4)*8+j], B-frag: B[k=(lane>>4)*8+j][n=lane&15]
//   C/D:    col=lane&15, row=(lane>>4)*4+reg

typedef __bf16 bf16x8 __attribute__((ext_vector_type(8)));
typedef float f32x4 __attribute__((ext_vector_type(4)));
typedef __hip_bfloat16 bf16;

struct alignas(16) BF8 { bf16 h[8]; };

constexpr int BATCH = 64;
constexpr int NP    = 196;
constexpr int NPAD  = 256;
constexpr int DIM   = 768;
constexpr int NT    = 8;
constexpr size_t MSZ = (size_t)DIM * DIM;
constexpr int KT    = 24;    // K tiles of 32

__device__ __forceinline__ void async_cp16(const void* g, void* l) {
  __builtin_amdgcn_global_load_lds(
      (const __attribute__((address_space(1))) uint32_t*)g,
      (__attribute__((address_space(3))) uint32_t*)l, 16, 0, 0);
}

// ---------------- K1: patchify + cast to bf16, pad rows to 256 ----------------
__global__ void k_patchify(const float* __restrict__ x, bf16* __restrict__ A) {
  int idx  = blockIdx.x * blockDim.x + threadIdx.x;
  int col4 = idx % (DIM / 4);
  int row  = idx / (DIM / 4);
  int d = col4 * 4;
  int b = row >> 8;
  int n = row & 255;
  bf16 tmp[4];
  if (n < NP) {
    int hp = n / 14, wp = n % 14;
    int c  = d >> 8;
    int rr = d & 255;
    int i = rr >> 4, j = rr & 15;
    const float* src = x + ((((size_t)b * 3 + c) * 224 + hp * 16 + i) * 224 + wp * 16 + j);
    float4 f = *(const float4*)src;
    tmp[0] = __float2bfloat16(f.x);
    tmp[1] = __float2bfloat16(f.y);
    tmp[2] = __float2bfloat16(f.z);
    tmp[3] = __float2bfloat16(f.w);
  } else {
    tmp[0] = tmp[1] = tmp[2] = tmp[3] = __float2bfloat16(0.0f);
  }
  *(ushort4*)(A + (size_t)row * DIM + d) = *(ushort4*)tmp;
}

// ---------------- K2: transpose + cast weights: WT[mat][n][k] = W[mat][k][n] ----------------
__global__ void k_transpose_cast(const float* __restrict__ W1, const float* __restrict__ dW1,
                                 const float* __restrict__ W2, const float* __restrict__ dW2,
                                 bf16* __restrict__ WT) {
  __shared__ float tile[32][33];
  int mat = blockIdx.z;
  const float* src;
  if      (mat == 0) src = W1;
  else if (mat <= 8) src = dW1 + (size_t)(mat - 1) * MSZ;
  else if (mat == 9) src = W2;
  else               src = dW2 + (size_t)(mat - 10) * MSZ;
  int n0 = blockIdx.x * 32;
  int k0 = blockIdx.y * 32;
  int tx = threadIdx.x & 31, ty = threadIdx.x >> 5;
#pragma unroll
  for (int r = ty; r < 32; r += 8)
    tile[r][tx] = src[(size_t)(k0 + r) * DIM + n0 + tx];
  __syncthreads();
  bf16* dst = WT + (size_t)mat * MSZ;
#pragma unroll
  for (int r = ty; r < 32; r += 8)
    dst[(size_t)(n0 + r) * DIM + k0 + tx] = __float2bfloat16(tile[tx][r]);
}

// ---------------- K3: pipelined per-sample-pair GEMM (+inline mix) + relu + pool -------------
// grid dim3(12 ntiles, 2 rowblocks, 32 sample-pairs) = 768 blocks (3/CU).
// Block: 2 samples x 128 rows x 64 cols. Waves: sample = w&1, rowhalf = w>>1,
// 64x64 per wave -> acc 4x4, 16 MFMA/iter, BK=32, KT=24.
// LDS slot (16B granules): A p = s*512 + row*4 + cs (data granule c = cs^(row&3));
// B q = s*256 + row*4 + cs (MIX) or q = row*4 + cs (shared).

template<int MIX>
__device__ __forceinline__ void stage_tile(const bf16* __restrict__ A, const bf16* __restrict__ WT,
                                           int b0, int rowbase, int n0, int kk,
                                           int wave, int lane, int tid,
                                           uint4* __restrict__ Ab, uint4* __restrict__ Bb,
                                           const float* __restrict__ c0,
                                           const float* __restrict__ c1) {
  if (MIX) {
    // 1. weight-granule loads (one granule serves both samples)
    int r = tid >> 2, cp = tid & 3, c = cp ^ (r & 3);
    const bf16* p0 = WT + (size_t)(n0 + r) * DIM + kk + c * 8;
    BF8 w = *(const BF8*)p0;
    BF8 dv[8];
#pragma unroll
    for (int t = 0; t < NT; t++) dv[t] = *(const BF8*)(p0 + (size_t)(1 + t) * MSZ);
    asm volatile("" ::: "memory");   // keep mix loads above the async issues
    // 2. async A for this tile (LDS dst wave-uniform; HW adds lane*16)
#pragma unroll
    for (int i = 0; i < 4; i++) {
      int p = wave * 256 + i * 64 + lane;
      int s = p >> 9, rr = (p >> 2) & 127, cc = (p & 3) ^ (rr & 3);
      async_cp16(A + ((size_t)(b0 + s) * NPAD + rowbase + rr) * DIM + kk + cc * 8,
                 (void*)(Ab + wave * 256 + i * 64));
    }
    // 3. mix (compiler's vmcnt wait here retires the OLDER tile-k asyncs)
    float m0[8], m1[8];
#pragma unroll
    for (int j = 0; j < 8; j++) { float wv = __bfloat162float(w.h[j]); m0[j] = wv; m1[j] = wv; }
#pragma unroll
    for (int t = 0; t < NT; t++) {
#pragma unroll
      for (int j = 0; j < 8; j++) {
        float d = __bfloat162float(dv[t].h[j]);
        m0[j] += c0[t] * d;
        m1[j] += c1[t] * d;
      }
    }
    BF8 o0, o1;
#pragma unroll
    for (int j = 0; j < 8; j++) { o0.h[j] = __float2bfloat16(m0[j]); o1.h[j] = __float2bfloat16(m1[j]); }
    Bb[tid]       = *(uint4*)&o0;
    Bb[256 + tid] = *(uint4*)&o1;
    asm volatile("s_waitcnt lgkmcnt(0)" ::: "memory");
  } else {
    // async A (4/wave) + async B (1/wave) = 5 loads/wave
#pragma unroll
    for (int i = 0; i < 4; i++) {
      int p = wave * 256 + i * 64 + lane;
      int s = p >> 9, rr = (p >> 2) & 127, cc = (p & 3) ^ (rr & 3);
      async_cp16(A + ((size_t)(b0 + s) * NPAD + rowbase + rr) * DIM + kk + cc * 8,
                 (void*)(Ab + wave * 256 + i * 64));
    }
    int q = wave * 64 + lane;
    int r = q >> 2, c = (q & 3) ^ (r & 3);
    async_cp16(WT + (size_t)(n0 + r) * DIM + kk + c * 8, (void*)(Bb + wave * 64));
  }
}

template<int MIX>
__global__ __launch_bounds__(256, 3)
void k_gemm_pool(const bf16* __restrict__ A,    // [64*256, 768]
                 const bf16* __restrict__ WT,   // mats 0..8 = W1T, dW1T[8]
                 const float* __restrict__ b1,
                 const float* __restrict__ db1,
                 const float* __restrict__ coefs,  // [64][8] (MIX only)
                 float* __restrict__ pooled) {     // f32 [64][768], pre-zeroed, atomicAdd
  __shared__ uint4 AslU[2][1024];   // [buf][s*512 + row*4 + swz(cs)]   32KB
  __shared__ uint4 BslU[2][512];    // [buf][(s*256|0) + row*4 + swz(cs)] 16KB
  __shared__ float biasl[2][64];
  __shared__ float clS[2][NT];
  __shared__ float red[4][64];

  int nt = blockIdx.x, rb = blockIdx.y, sg = blockIdx.z;
  int n0 = nt * 64, rowbase = rb * 128, b0 = sg * 2;
  int tid = threadIdx.x;

  float c0[NT], c1[NT];
  if (MIX) {
    if (tid < 16) clS[tid >> 3][tid & 7] = coefs[(b0 + (tid >> 3)) * NT + (tid & 7)];
    __syncthreads();
#pragma unroll
    for (int t = 0; t < NT; t++) { c0[t] = clS[0][t]; c1[t] = clS[1][t]; }
  }
  if (tid < 128) {
    int s = tid >> 6, col = tid & 63;
    float bias = b1[n0 + col];
    if (MIX) {
#pragma unroll
      for (int t = 0; t < NT; t++) bias += clS[s][t] * db1[t * DIM + n0 + col];
    }
    biasl[s][col] = bias;
  }

  int wave = tid >> 6, lane = tid & 63;
  int quad = lane >> 4, l16 = lane & 15;
  int s = wave & 1, half = wave >> 1;
  f32x4 acc[4][4] = {};

  // prologue: stage tile 0 into buf 0
  stage_tile<MIX>(A, WT, b0, rowbase, n0, 0, wave, lane, tid, AslU[0], BslU[0], c0, c1);

  int buf = 0;
  for (int kt = 0; kt < KT; kt++) {
    if (kt + 1 < KT) {
      stage_tile<MIX>(A, WT, b0, rowbase, n0, (kt + 1) * 32, wave, lane, tid,
                      AslU[buf ^ 1], BslU[buf ^ 1], c0, c1);
      if (!MIX) asm volatile("s_waitcnt vmcnt(5)" ::: "memory");
    } else {
      asm volatile("s_waitcnt vmcnt(0)" ::: "memory");
    }
    __builtin_amdgcn_s_barrier();
    // MFMA on buf: 4 mf x 4 nf (BK=32 -> one k-step)
    const uint4* Ab = AslU[buf];
    const uint4* Bb = BslU[buf];
    bf16x8 bfr[4];
#pragma unroll
    for (int nf = 0; nf < 4; nf++) {
      int brow = nf * 16 + l16;
      bfr[nf] = *(const bf16x8*)(Bb + (MIX ? s * 256 : 0) + brow * 4 + (quad ^ (brow & 3)));
    }
#pragma unroll
    for (int mf = 0; mf < 4; mf++) {
      int arow = half * 64 + mf * 16 + l16;
      bf16x8 af = *(const bf16x8*)(Ab + s * 512 + arow * 4 + (quad ^ (arow & 3)));
#pragma unroll
      for (int nf = 0; nf < 4; nf++)
        acc[mf][nf] = __builtin_amdgcn_mfma_f32_16x16x32_bf16(af, bfr[nf], acc[mf][nf], 0, 0, 0);
    }
    __builtin_amdgcn_s_barrier();
    buf ^= 1;
  }

  // epilogue: relu(acc + bias), mask pad rows, column sums
  float colsum[4];
#pragma unroll
  for (int nf = 0; nf < 4; nf++) {
    float bias = biasl[s][nf * 16 + l16];
    float sum = 0.0f;
#pragma unroll
    for (int mf = 0; mf < 4; mf++) {
      int rbase = rowbase + half * 64 + mf * 16 + quad * 4;
#pragma unroll
      for (int r = 0; r < 4; r++) {
        if (rbase + r < NP) sum += fmaxf(acc[mf][nf][r] + bias, 0.0f);
      }
    }
    sum += __shfl_xor(sum, 16, 64);
    sum += __shfl_xor(sum, 32, 64);
    colsum[nf] = sum;
  }
  if (lane < 16) {
#pragma unroll
    for (int nf = 0; nf < 4; nf++) red[wave][nf * 16 + lane] = colsum[nf];
  }
  __syncthreads();
  if (tid < 128) {
    int ss = tid >> 6, col = tid & 63;
    float v = red[ss][col] + red[ss + 2][col];   // two row-halves of sample ss
    atomicAdd(pooled + (size_t)(b0 + ss) * DIM + n0 + col, v * (1.0f / 196.0f));
  }
}

// ---------------- K5: small GEMM, M=64: Y[mat] = Af(f32->bf16) @ WT[matbase+mat] ------------
__global__ __launch_bounds__(256, 2)
void k_gemm2(const float* __restrict__ Af,    // [64][768] f32
             const bf16* __restrict__ WT,
             int matbase,
             const float* __restrict__ bias,  // [768] or null
             float* __restrict__ Y) {         // [nmat][64][768]
  __shared__ uint4 AslU[64 * 8];
  __shared__ uint4 BslU[64 * 8];
  int n0  = blockIdx.x * 64;
  int mat = blockIdx.y;
  int tid = threadIdx.x, wave = tid >> 6, lane = tid & 63;
  int quad = lane >> 4, l16 = lane & 15;
  f32x4 acc[4] = {};
  const bf16* Wm = WT + (size_t)(matbase + mat) * MSZ;
  for (int k0 = 0; k0 < DIM; k0 += 64) {
#pragma unroll
    for (int i = 0; i < 2; i++) {
      int g = tid + i * 256;
      int r = g >> 3, c = g & 7;
      const float* src = Af + (size_t)r * DIM + k0 + c * 8;
      float4 xa = ((const float4*)src)[0];
      float4 xb = ((const float4*)src)[1];
      BF8 o;
      o.h[0] = __float2bfloat16(xa.x); o.h[1] = __float2bfloat16(xa.y);
      o.h[2] = __float2bfloat16(xa.z); o.h[3] = __float2bfloat16(xa.w);
      o.h[4] = __float2bfloat16(xb.x); o.h[5] = __float2bfloat16(xb.y);
      o.h[6] = __float2bfloat16(xb.z); o.h[7] = __float2bfloat16(xb.w);
      AslU[r * 8 + (c ^ (r & 7))] = *(uint4*)&o;
      BslU[r * 8 + (c ^ (r & 7))] = *(const uint4*)(Wm + (size_t)(n0 + r) * DIM + k0 + c * 8);
    }
    __syncthreads();
    const bf16* As = (const bf16*)AslU;
    const bf16* Bs = (const bf16*)BslU;
#pragma unroll
    for (int ks = 0; ks < 2; ks++) {
      int brow = wave * 16 + l16;
      bf16x8 bfr = *(const bf16x8*)(Bs + (size_t)(brow * 8 + ((ks * 4 + quad) ^ (brow & 7))) * 8);
#pragma unroll
      for (int mf = 0; mf < 4; mf++) {
        int arow = mf * 16 + l16;
        bf16x8 af = *(const bf16x8*)(As + (size_t)(arow * 8 + ((ks * 4 + quad) ^ (arow & 7))) * 8);
        acc[mf] = __builtin_amdgcn_mfma_f32_16x16x32_bf16(af, bfr, acc[mf], 0, 0, 0);
      }
    }
    __syncthreads();
  }
#pragma unroll
  for (int mf = 0; mf < 4; mf++) {
#pragma unroll
    for (int r = 0; r < 4; r++) {
      int row = mf * 16 + quad * 4 + r;
      int col = n0 + wave * 16 + l16;
      float v = acc[mf][r];
      if (bias) v += bias[col];
      Y[((size_t)mat * 64 + row) * DIM + col] = v;
    }
  }
}

// ---------------- K6: MetaNet ----------------
__global__ void k_metanet(const float* __restrict__ base,
                          const float* __restrict__ mw1, const float* __restrict__ mb1,
                          const float* __restrict__ mw2, const float* __restrict__ mb2,
                          float* __restrict__ coefs) {
  __shared__ float bl[DIM];
  __shared__ float hl[192];
  int b = blockIdx.x, tid = threadIdx.x;   // 192 threads
  for (int i = tid; i < DIM; i += 192) bl[i] = base[(size_t)b * DIM + i];
  __syncthreads();
  float s = mb1[tid];
  for (int k = 0; k < DIM; k++) s += bl[k] * mw1[(size_t)k * 192 + tid];
  hl[tid] = fmaxf(s, 0.0f);
  __syncthreads();
  if (tid < NT) {
    float c = mb2[tid];
    for (int j = 0; j < 192; j++) c += hl[j] * mw2[(size_t)j * NT + tid];
    coefs[b * NT + tid] = c;
  }
}

// ---------------- K7: combine ----------------
__global__ void k_combine(const float* __restrict__ Y,
                          const float* __restrict__ coefs,
                          const float* __restrict__ b2,
                          const float* __restrict__ db2,
                          float* __restrict__ out) {
  int idx = blockIdx.x * 256 + threadIdx.x;
  int b = idx / DIM, e = idx % DIM;
  float v = Y[(size_t)b * DIM + e] + b2[e];
#pragma unroll
  for (int t = 0; t < NT; t++) {
    float c = coefs[b * NT + t];
    v += c * (Y[((size_t)(1 + t) * 64 + b) * DIM + e] + db2[(size_t)t * DIM + e]);
  }
  out[idx] = v;
}

extern "C" void kernel_launch(void* const* d_in, const int* in_sizes, int n_in,
                              void* d_out, int out_size, void* d_ws, size_t ws_size,
                              hipStream_t stream) {
  const float* x   = (const float*)d_in[0];
  const float* W1  = (const float*)d_in[1];
  const float* b1  = (const float*)d_in[2];
  const float* W2  = (const float*)d_in[3];
  const float* b2  = (const float*)d_in[4];
  const float* dW1 = (const float*)d_in[5];
  const float* db1 = (const float*)d_in[6];
  const float* dW2 = (const float*)d_in[7];
  const float* db2 = (const float*)d_in[8];
  const float* mw1 = (const float*)d_in[9];
  const float* mb1 = (const float*)d_in[10];
  const float* mw2 = (const float*)d_in[11];
  const float* mb2 = (const float*)d_in[12];
  float* out = (float*)d_out;
  (void)in_sizes; (void)n_in; (void)out_size; (void)ws_size;

  // workspace layout (bytes) — total ~48.8 MB
  char* ws = (char*)d_ws;
  bf16*  A_bf    = (bf16*) (ws);                 // 25,165,824
  bf16*  WT      = (bf16*) (ws + 25165824);      // 21,233,664 -> 46,399,488
  float* pooledA = (float*)(ws + 46399488);      //    196,608 -> 46,596,096
  float* pooledB = (float*)(ws + 46596096);      //    196,608 -> 46,792,704
  float* coefs   = (float*)(ws + 46792704);      //      2,048 -> 46,794,752
  float* base    = (float*)(ws + 46794752);      //    196,608 -> 46,991,360
  float* Y       = (float*)(ws + 46991360);      //  1,769,472 -> 48,760,832

  // zero pooled accumulators (pooledA+pooledB contiguous)
  hipMemsetAsync(pooledA, 0, 2 * 196608, stream);

  k_patchify<<<dim3((BATCH * NPAD * (DIM / 4)) / 256), 256, 0, stream>>>(x, A_bf);
  k_transpose_cast<<<dim3(24, 24, 18), 256, 0, stream>>>(W1, dW1, W2, dW2, WT);
  // phase A
  k_gemm_pool<0><<<dim3(12, 2, 32), 256, 0, stream>>>(A_bf, WT, b1, db1, nullptr, pooledA);
  k_gemm2<<<dim3(DIM / 64, 1), 256, 0, stream>>>(pooledA, WT, 9, b2, base);
  k_metanet<<<dim3(BATCH), 192, 0, stream>>>(base, mw1, mb1, mw2, mb2, coefs);
  // phase B (pipelined inline mix, 2 samples/block)
  k_gemm_pool<1><<<dim3(12, 2, 32), 256, 0, stream>>>(A_bf, WT, b1, db1, coefs, pooledB);
  k_gemm2<<<dim3(DIM / 64, 9), 256, 0, stream>>>(pooledB, WT, 9, nullptr, Y);
  k_combine<<<dim3((BATCH * DIM) / 256), 256, 0, stream>>>(Y, coefs, b2, db2, out);
}

// Round 8
// 335.684 us; speedup vs baseline: 1.8825x; 1.5989x over previous
//
#include <hip/hip_runtime.h>
#include <hip/hip_bf16.h>

// MetaNetImageEncoder on MI355X — round 8.
// Model (r1-r7 evidence): k_gemm_pool time ∝ L2/L3 bytes moved (~11 TB/s
// effective), not barrier count — r1 (bulk-sync BK32) == r4 (async BK64) ==
// 88us at ~964MB logical traffic; r6/r7's ntile-fastest grid broke per-XCD
// locality (FETCH 54->884MB). This round cuts bytes and restores locality:
//  * G=2 samples/block in phase B: weights mixed once per pair (664->340MB).
//  * NPAD 224 (was 256): A 25->22MB, -12.5% pad waste.
//  * Phase A BN=128: A re-reads 300->132MB (total 375->206MB).
//  * samples-major grid (bid%8 = sample%8, r4-proven XCD sliding window).
//  * BK=32 swizzle fixed: slot c' = c ^ ((r>>1)&3) -> 8 banks 2-way (free);
//    r6/r7's c^(r&3) was 4 banks 4-way (2.36M conflicts).
//  * bulk-sync k-loop, wave-uniform async global_load_lds staging (r4-proven).
//
// MFMA 16x16x32 bf16 layouts (learn_hip m89):
//   A-frag: A[m=lane&15][k=(lane>>4)*8+j], B-frag: B[k=(lane>>4)*8+j][n=lane&15]
//   C/D:    col=lane&15, row=(lane>>4)*4+reg

typedef __bf16 bf16x8 __attribute__((ext_vector_type(8)));
typedef float f32x4 __attribute__((ext_vector_type(4)));
typedef __hip_bfloat16 bf16;

struct alignas(16) BF8 { bf16 h[8]; };

constexpr int BATCH = 64;
constexpr int NP    = 196;
constexpr int NPAD  = 224;     // 14 mfrags of 16
constexpr int DIM   = 768;
constexpr int NT    = 8;
constexpr size_t MSZ = (size_t)DIM * DIM;
constexpr int KT    = 24;      // K tiles of 32

__device__ __forceinline__ void async_cp16(const void* g, void* l) {
  __builtin_amdgcn_global_load_lds(
      (const __attribute__((address_space(1))) uint32_t*)g,
      (__attribute__((address_space(3))) uint32_t*)l, 16, 0, 0);
}

// ---------------- K1: patchify + cast to bf16, pad rows to 224 ----------------
__global__ void k_patchify(const float* __restrict__ x, bf16* __restrict__ A) {
  int idx  = blockIdx.x * blockDim.x + threadIdx.x;   // 64*224*192
  int col4 = idx % (DIM / 4);
  int row  = idx / (DIM / 4);
  int d = col4 * 4;
  int b = row / NPAD;
  int n = row % NPAD;
  bf16 tmp[4];
  if (n < NP) {
    int hp = n / 14, wp = n % 14;
    int c  = d >> 8;
    int rr = d & 255;
    int i = rr >> 4, j = rr & 15;
    const float* src = x + ((((size_t)b * 3 + c) * 224 + hp * 16 + i) * 224 + wp * 16 + j);
    float4 f = *(const float4*)src;
    tmp[0] = __float2bfloat16(f.x);
    tmp[1] = __float2bfloat16(f.y);
    tmp[2] = __float2bfloat16(f.z);
    tmp[3] = __float2bfloat16(f.w);
  } else {
    tmp[0] = tmp[1] = tmp[2] = tmp[3] = __float2bfloat16(0.0f);
  }
  *(ushort4*)(A + (size_t)row * DIM + d) = *(ushort4*)tmp;
}

// ---------------- K2: transpose + cast weights: WT[mat][n][k] = W[mat][k][n] ----------------
__global__ void k_transpose_cast(const float* __restrict__ W1, const float* __restrict__ dW1,
                                 const float* __restrict__ W2, const float* __restrict__ dW2,
                                 bf16* __restrict__ WT) {
  __shared__ float tile[32][33];
  int mat = blockIdx.z;
  const float* src;
  if      (mat == 0) src = W1;
  else if (mat <= 8) src = dW1 + (size_t)(mat - 1) * MSZ;
  else if (mat == 9) src = W2;
  else               src = dW2 + (size_t)(mat - 10) * MSZ;
  int n0 = blockIdx.x * 32;
  int k0 = blockIdx.y * 32;
  int tx = threadIdx.x & 31, ty = threadIdx.x >> 5;
#pragma unroll
  for (int r = ty; r < 32; r += 8)
    tile[r][tx] = src[(size_t)(k0 + r) * DIM + n0 + tx];
  __syncthreads();
  bf16* dst = WT + (size_t)mat * MSZ;
#pragma unroll
  for (int r = ty; r < 32; r += 8)
    dst[(size_t)(n0 + r) * DIM + k0 + tx] = __float2bfloat16(tile[tx][r]);
}

// ---------------- K3a: phase A GEMM + relu + pool. block = 1 sample x 224r x 128n -----------
// grid (64 samples, 6 ntiles) samples-major. 4 waves: rh = w>>1 (112 rows), ch = w&1 (64 cols).
// acc[7][4] = 112 f32. BK=32, 24 iters. LDS granule slot(r,c') holds source granule
// c = c' ^ ((r>>1)&3)  -> 8-bank 2-way reads (free).
__global__ __launch_bounds__(256, 3)
void k_gemm_poolA(const bf16* __restrict__ A,    // [64*224, 768]
                  const bf16* __restrict__ WT,   // mat 0 = W1T
                  const float* __restrict__ b1,
                  float* __restrict__ pooled) {  // f32 [64][768]
  __shared__ uint4 Asl[NPAD * 4];    // 224 rows x 4 granules = 14 KB
  __shared__ uint4 Bsl[128 * 4];     // 128 rows x 4 granules =  8 KB
  __shared__ float red[2][128];

  int b  = blockIdx.x;
  int n0 = blockIdx.y * 128;
  int tid = threadIdx.x, wave = tid >> 6, lane = tid & 63;
  int quad = lane >> 4, l16 = lane & 15;
  int rh = wave >> 1, ch = wave & 1;
  f32x4 acc[7][4] = {};
  const bf16* Ag = A + (size_t)b * NPAD * DIM;

  for (int kt = 0; kt < KT; kt++) {
    int kk = kt * 32;
    // stage A: 14 issues of 16 rows (wave-uniform LDS dst)
#pragma unroll
    for (int i = 0; i < 4; i++) {
      int idx = wave * 4 + i;
      if (idx < 14) {
        int r = idx * 16 + (lane >> 2);
        int c = (lane & 3) ^ ((r >> 1) & 3);
        async_cp16(Ag + (size_t)r * DIM + kk + c * 8, (void*)(Asl + idx * 64));
      }
    }
    // stage B: 8 issues of 16 rows
#pragma unroll
    for (int i = 0; i < 2; i++) {
      int idx = wave * 2 + i;
      int r = idx * 16 + (lane >> 2);
      int c = (lane & 3) ^ ((r >> 1) & 3);
      async_cp16(WT + (size_t)(n0 + r) * DIM + kk + c * 8, (void*)(Bsl + idx * 64));
    }
    __syncthreads();   // drains vmcnt before LDS reads
    bf16x8 bfr[4];
#pragma unroll
    for (int nf = 0; nf < 4; nf++) {
      int brow = ch * 64 + nf * 16 + l16;
      bfr[nf] = *(const bf16x8*)(Bsl + brow * 4 + (quad ^ ((brow >> 1) & 3)));
    }
#pragma unroll
    for (int mf = 0; mf < 7; mf++) {
      int arow = rh * 112 + mf * 16 + l16;
      bf16x8 af = *(const bf16x8*)(Asl + arow * 4 + (quad ^ ((arow >> 1) & 3)));
#pragma unroll
      for (int nf = 0; nf < 4; nf++)
        acc[mf][nf] = __builtin_amdgcn_mfma_f32_16x16x32_bf16(af, bfr[nf], acc[mf][nf], 0, 0, 0);
    }
    __syncthreads();
  }

  // epilogue: relu(acc + bias), mask pad rows, column sums
  float colsum[4];
#pragma unroll
  for (int nf = 0; nf < 4; nf++) {
    float bias = b1[n0 + ch * 64 + nf * 16 + l16];
    float s = 0.0f;
#pragma unroll
    for (int mf = 0; mf < 7; mf++) {
      int rbase = rh * 112 + mf * 16 + quad * 4;
#pragma unroll
      for (int r = 0; r < 4; r++) {
        if (rbase + r < NP) s += fmaxf(acc[mf][nf][r] + bias, 0.0f);
      }
    }
    s += __shfl_xor(s, 16, 64);
    s += __shfl_xor(s, 32, 64);
    colsum[nf] = s;
  }
  if (lane < 16) {
#pragma unroll
    for (int nf = 0; nf < 4; nf++) red[rh][ch * 64 + nf * 16 + lane] = colsum[nf];
  }
  __syncthreads();
  if (tid < 128)
    pooled[(size_t)b * DIM + n0 + tid] = (red[0][tid] + red[1][tid]) * (1.0f / 196.0f);
}

// ---------------- K3b: phase B GEMM (G=2 inline mix) + relu + pool ----------------
// grid (32 pairs, 12 ntiles) samples-major. block = 2 samples x 224r x 64n.
// 4 waves: s = w&1, rh = w>>1 (112 rows). acc[7][4]. Weights mixed ONCE per pair.
__global__ __launch_bounds__(256, 2)
void k_gemm_poolB(const bf16* __restrict__ A,    // [64*224, 768]
                  const bf16* __restrict__ WT,   // mats 0..8 = W1T, dW1T[8]
                  const float* __restrict__ b1,
                  const float* __restrict__ db1,
                  const float* __restrict__ coefs,  // [64][8]
                  float* __restrict__ pooled) {     // f32 [64][768]
  __shared__ uint4 Asl[2 * NPAD * 4];   // [s][224 rows][4 granules] = 28 KB
  __shared__ uint4 Bsl[2][256];         // [s][64 rows x 4 granules] = 8 KB
  __shared__ float clS[2][NT];
  __shared__ float biasl[2][64];
  __shared__ float red[4][64];

  int pr = blockIdx.x, nt = blockIdx.y;
  int n0 = nt * 64, b0 = pr * 2;
  int tid = threadIdx.x;

  if (tid < 16) clS[tid >> 3][tid & 7] = coefs[(b0 + (tid >> 3)) * NT + (tid & 7)];
  __syncthreads();
  float c0[NT], c1[NT];
#pragma unroll
  for (int t = 0; t < NT; t++) { c0[t] = clS[0][t]; c1[t] = clS[1][t]; }
  if (tid < 128) {
    int s = tid >> 6, col = tid & 63;
    float bias = b1[n0 + col];
#pragma unroll
    for (int t = 0; t < NT; t++) bias += clS[s][t] * db1[t * DIM + n0 + col];
    biasl[s][col] = bias;
  }

  int wave = tid >> 6, lane = tid & 63;
  int quad = lane >> 4, l16 = lane & 15;
  int s = wave & 1, rh = wave >> 1;
  f32x4 acc[7][4] = {};

  for (int kt = 0; kt < KT; kt++) {
    int kk = kt * 32;
    // stage A: 28 issues of 16 rows, 7 per wave (wave-uniform LDS dst)
#pragma unroll
    for (int i = 0; i < 7; i++) {
      int j  = wave * 7 + i;           // 0..27
      int ss = (j >= 14) ? 1 : 0;
      int jj = j - ss * 14;            // 0..13
      int r  = jj * 16 + (lane >> 2);  // 0..223
      int c  = (lane & 3) ^ ((r >> 1) & 3);
      async_cp16(A + ((size_t)(b0 + ss) * NPAD + r) * DIM + kk + c * 8,
                 (void*)(Asl + ss * (NPAD * 4) + jj * 64));
    }
    // mix B: thread t -> granule (r = t>>2, c' = t&3); outputs for both samples
    {
      int r = tid >> 2, c = (tid & 3) ^ ((r >> 1) & 3);
      const bf16* p0 = WT + (size_t)(n0 + r) * DIM + kk + c * 8;
      BF8 w = *(const BF8*)p0;
      BF8 dv[NT];
#pragma unroll
      for (int t = 0; t < NT; t++) dv[t] = *(const BF8*)(p0 + (size_t)(1 + t) * MSZ);
      float m0[8], m1[8];
#pragma unroll
      for (int j = 0; j < 8; j++) { float wv = __bfloat162float(w.h[j]); m0[j] = wv; m1[j] = wv; }
#pragma unroll
      for (int t = 0; t < NT; t++) {
#pragma unroll
        for (int j = 0; j < 8; j++) {
          float d = __bfloat162float(dv[t].h[j]);
          m0[j] += c0[t] * d;
          m1[j] += c1[t] * d;
        }
      }
      BF8 o0, o1;
#pragma unroll
      for (int j = 0; j < 8; j++) { o0.h[j] = __float2bfloat16(m0[j]); o1.h[j] = __float2bfloat16(m1[j]); }
      Bsl[0][tid] = *(uint4*)&o0;
      Bsl[1][tid] = *(uint4*)&o1;
    }
    __syncthreads();   // drains vmcnt (async A) + lgkm (ds_write)
    bf16x8 bfr[4];
#pragma unroll
    for (int nf = 0; nf < 4; nf++) {
      int brow = nf * 16 + l16;
      bfr[nf] = *(const bf16x8*)(&Bsl[s][brow * 4 + (quad ^ ((brow >> 1) & 3))]);
    }
#pragma unroll
    for (int mf = 0; mf < 7; mf++) {
      int arow = rh * 112 + mf * 16 + l16;
      bf16x8 af = *(const bf16x8*)(Asl + s * (NPAD * 4) + arow * 4 + (quad ^ ((arow >> 1) & 3)));
#pragma unroll
      for (int nf = 0; nf < 4; nf++)
        acc[mf][nf] = __builtin_amdgcn_mfma_f32_16x16x32_bf16(af, bfr[nf], acc[mf][nf], 0, 0, 0);
    }
    __syncthreads();
  }

  // epilogue
  float colsum[4];
#pragma unroll
  for (int nf = 0; nf < 4; nf++) {
    float bias = biasl[s][nf * 16 + l16];
    float sum = 0.0f;
#pragma unroll
    for (int mf = 0; mf < 7; mf++) {
      int rbase = rh * 112 + mf * 16 + quad * 4;
#pragma unroll
      for (int r = 0; r < 4; r++) {
        if (rbase + r < NP) sum += fmaxf(acc[mf][nf][r] + bias, 0.0f);
      }
    }
    sum += __shfl_xor(sum, 16, 64);
    sum += __shfl_xor(sum, 32, 64);
    colsum[nf] = sum;
  }
  if (lane < 16) {
#pragma unroll
    for (int nf = 0; nf < 4; nf++) red[wave][nf * 16 + lane] = colsum[nf];
  }
  __syncthreads();
  if (tid < 128) {
    int ss = tid >> 6, col = tid & 63;
    float v = red[ss][col] + red[ss + 2][col];
    pooled[(size_t)(b0 + ss) * DIM + n0 + col] = v * (1.0f / 196.0f);
  }
}

// ---------------- K5: small GEMM, M=64: Y[mat] = Af(f32->bf16) @ WT[matbase+mat] ------------
__global__ __launch_bounds__(256, 2)
void k_gemm2(const float* __restrict__ Af,    // [64][768] f32
             const bf16* __restrict__ WT,
             int matbase,
             const float* __restrict__ bias,  // [768] or null
             float* __restrict__ Y) {         // [nmat][64][768]
  __shared__ uint4 AslU[64 * 8];
  __shared__ uint4 BslU[64 * 8];
  int n0  = blockIdx.x * 64;
  int mat = blockIdx.y;
  int tid = threadIdx.x, wave = tid >> 6, lane = tid & 63;
  int quad = lane >> 4, l16 = lane & 15;
  f32x4 acc[4] = {};
  const bf16* Wm = WT + (size_t)(matbase + mat) * MSZ;
  for (int k0 = 0; k0 < DIM; k0 += 64) {
#pragma unroll
    for (int i = 0; i < 2; i++) {
      int g = tid + i * 256;
      int r = g >> 3, c = g & 7;
      const float* src = Af + (size_t)r * DIM + k0 + c * 8;
      float4 xa = ((const float4*)src)[0];
      float4 xb = ((const float4*)src)[1];
      BF8 o;
      o.h[0] = __float2bfloat16(xa.x); o.h[1] = __float2bfloat16(xa.y);
      o.h[2] = __float2bfloat16(xa.z); o.h[3] = __float2bfloat16(xa.w);
      o.h[4] = __float2bfloat16(xb.x); o.h[5] = __float2bfloat16(xb.y);
      o.h[6] = __float2bfloat16(xb.z); o.h[7] = __float2bfloat16(xb.w);
      AslU[r * 8 + (c ^ (r & 7))] = *(uint4*)&o;
      BslU[r * 8 + (c ^ (r & 7))] = *(const uint4*)(Wm + (size_t)(n0 + r) * DIM + k0 + c * 8);
    }
    __syncthreads();
    const bf16* As = (const bf16*)AslU;
    const bf16* Bs = (const bf16*)BslU;
#pragma unroll
    for (int ks = 0; ks < 2; ks++) {
      int brow = wave * 16 + l16;
      bf16x8 bfr = *(const bf16x8*)(Bs + (size_t)(brow * 8 + ((ks * 4 + quad) ^ (brow & 7))) * 8);
#pragma unroll
      for (int mf = 0; mf < 4; mf++) {
        int arow = mf * 16 + l16;
        bf16x8 af = *(const bf16x8*)(As + (size_t)(arow * 8 + ((ks * 4 + quad) ^ (arow & 7))) * 8);
        acc[mf] = __builtin_amdgcn_mfma_f32_16x16x32_bf16(af, bfr, acc[mf], 0, 0, 0);
      }
    }
    __syncthreads();
  }
#pragma unroll
  for (int mf = 0; mf < 4; mf++) {
#pragma unroll
    for (int r = 0; r < 4; r++) {
      int row = mf * 16 + quad * 4 + r;
      int col = n0 + wave * 16 + l16;
      float v = acc[mf][r];
      if (bias) v += bias[col];
      Y[((size_t)mat * 64 + row) * DIM + col] = v;
    }
  }
}

// ---------------- K6: MetaNet ----------------
__global__ void k_metanet(const float* __restrict__ base,
                          const float* __restrict__ mw1, const float* __restrict__ mb1,
                          const float* __restrict__ mw2, const float* __restrict__ mb2,
                          float* __restrict__ coefs) {
  __shared__ float bl[DIM];
  __shared__ float hl[192];
  int b = blockIdx.x, tid = threadIdx.x;   // 192 threads
  for (int i = tid; i < DIM; i += 192) bl[i] = base[(size_t)b * DIM + i];
  __syncthreads();
  float s = mb1[tid];
  for (int k = 0; k < DIM; k++) s += bl[k] * mw1[(size_t)k * 192 + tid];
  hl[tid] = fmaxf(s, 0.0f);
  __syncthreads();
  if (tid < NT) {
    float c = mb2[tid];
    for (int j = 0; j < 192; j++) c += hl[j] * mw2[(size_t)j * NT + tid];
    coefs[b * NT + tid] = c;
  }
}

// ---------------- K7: combine ----------------
__global__ void k_combine(const float* __restrict__ Y,
                          const float* __restrict__ coefs,
                          const float* __restrict__ b2,
                          const float* __restrict__ db2,
                          float* __restrict__ out) {
  int idx = blockIdx.x * 256 + threadIdx.x;
  int b = idx / DIM, e = idx % DIM;
  float v = Y[(size_t)b * DIM + e] + b2[e];
#pragma unroll
  for (int t = 0; t < NT; t++) {
    float c = coefs[b * NT + t];
    v += c * (Y[((size_t)(1 + t) * 64 + b) * DIM + e] + db2[(size_t)t * DIM + e]);
  }
  out[idx] = v;
}

extern "C" void kernel_launch(void* const* d_in, const int* in_sizes, int n_in,
                              void* d_out, int out_size, void* d_ws, size_t ws_size,
                              hipStream_t stream) {
  const float* x   = (const float*)d_in[0];
  const float* W1  = (const float*)d_in[1];
  const float* b1  = (const float*)d_in[2];
  const float* W2  = (const float*)d_in[3];
  const float* b2  = (const float*)d_in[4];
  const float* dW1 = (const float*)d_in[5];
  const float* db1 = (const float*)d_in[6];
  const float* dW2 = (const float*)d_in[7];
  const float* db2 = (const float*)d_in[8];
  const float* mw1 = (const float*)d_in[9];
  const float* mb1 = (const float*)d_in[10];
  const float* mw2 = (const float*)d_in[11];
  const float* mb2 = (const float*)d_in[12];
  float* out = (float*)d_out;
  (void)in_sizes; (void)n_in; (void)out_size; (void)ws_size;

  // workspace layout (bytes) — total ~45.6 MB
  char* ws = (char*)d_ws;
  bf16*  A_bf    = (bf16*) (ws);                 // 64*224*768*2 = 22,020,096
  bf16*  WT      = (bf16*) (ws + 22020096);      // 21,233,664 -> 43,253,760
  float* pooledA = (float*)(ws + 43253760);      //    196,608 -> 43,450,368
  float* pooledB = (float*)(ws + 43450368);      //    196,608 -> 43,646,976
  float* coefs   = (float*)(ws + 43646976);      //      2,048 -> 43,649,024
  float* base    = (float*)(ws + 43649024);      //    196,608 -> 43,845,632
  float* Y       = (float*)(ws + 43845632);      //  1,769,472 -> 45,615,104

  k_patchify<<<dim3((BATCH * NPAD * (DIM / 4)) / 256), 256, 0, stream>>>(x, A_bf);
  k_transpose_cast<<<dim3(24, 24, 18), 256, 0, stream>>>(W1, dW1, W2, dW2, WT);
  // phase A: BN=128, samples-major grid
  k_gemm_poolA<<<dim3(BATCH, 6), 256, 0, stream>>>(A_bf, WT, b1, pooledA);
  k_gemm2<<<dim3(DIM / 64, 1), 256, 0, stream>>>(pooledA, WT, 9, b2, base);
  k_metanet<<<dim3(BATCH), 192, 0, stream>>>(base, mw1, mb1, mw2, mb2, coefs);
  // phase B: G=2 pairs, BN=64, samples-major grid
  k_gemm_poolB<<<dim3(BATCH / 2, 12), 256, 0, stream>>>(A_bf, WT, b1, db1, coefs, pooledB);
  k_gemm2<<<dim3(DIM / 64, 9), 256, 0, stream>>>(pooledB, WT, 9, nullptr, Y);
  k_combine<<<dim3((BATCH * DIM) / 256), 256, 0, stream>>>(Y, coefs, b2, db2, out);
}